// Round 7
// baseline (364.614 us; speedup 1.0000x reference)
//
#include <hip/hip_runtime.h>

using u16 = unsigned short;
using u32 = unsigned int;

typedef __attribute__((ext_vector_type(8))) __bf16 bf16x8;
typedef __attribute__((ext_vector_type(4))) float f32x4;
typedef __attribute__((ext_vector_type(16))) float f32x16;

#define DEVI __device__ __forceinline__

DEVI float bf2f(u16 u) {
  union { u32 i; float f; } v; v.i = ((u32)u) << 16; return v.f;
}
DEVI u16 f2bf(float f) {
  union { float f; u32 u; } v; v.f = f;
  u32 u = v.u;
  u32 r = (u + 0x7fffu + ((u >> 16) & 1u)) >> 16;
  return (u16)r;
}
// pack two f32 -> one u32 of 2x bf16 (compiler emits v_cvt_pk_bf16_f32)
DEVI u32 pkbf(float a, float b) {
  union { __bf16 h[2]; u32 u; } t;
  t.h[0] = (__bf16)a; t.h[1] = (__bf16)b;
  return t.u;
}

// async global->LDS, 16B per lane. LDS dest = wave-uniform base + lane*16.
DEVI void gload16(const u16* g, u16* l) {
  __builtin_amdgcn_global_load_lds(
      (const __attribute__((address_space(1))) void*)g,
      (__attribute__((address_space(3))) void*)l, 16, 0, 0);
}

// ---------------- cvt x: fp32 -> bf16, 8 elems/thread ----------------
__global__ __launch_bounds__(256) void cvt_bf16_f32(const float* __restrict__ in,
                                                    u16* __restrict__ out, int n8) {
  int i = blockIdx.x * 256 + threadIdx.x;
  if (i >= n8) return;
  const float4* fin = (const float4*)in;
  float4 a = fin[i * 2], b = fin[i * 2 + 1];
  u16 o[8] = {f2bf(a.x), f2bf(a.y), f2bf(a.z), f2bf(a.w),
              f2bf(b.x), f2bf(b.y), f2bf(b.z), f2bf(b.w)};
  ((uint4*)out)[i] = *(const uint4*)o;
}

// ------- 64x64 transpose+convert body: in[R][Cc] f32 -> out[Cc][R] bf16 -------
DEVI void tcvt64_body(const float* in, u16* out, int R, int Cc, int c0, int r0, int t,
                      u16 (*tile)[72]) {
  {
    int row = t >> 2, part = t & 3;
    const float* src = in + (size_t)(r0 + row) * Cc + c0 + part * 16;
    float4 f0 = ((const float4*)src)[0];
    float4 f1 = ((const float4*)src)[1];
    float4 f2 = ((const float4*)src)[2];
    float4 f3 = ((const float4*)src)[3];
    u16 v[16] = {f2bf(f0.x), f2bf(f0.y), f2bf(f0.z), f2bf(f0.w),
                 f2bf(f1.x), f2bf(f1.y), f2bf(f1.z), f2bf(f1.w),
                 f2bf(f2.x), f2bf(f2.y), f2bf(f2.z), f2bf(f2.w),
                 f2bf(f3.x), f2bf(f3.y), f2bf(f3.z), f2bf(f3.w)};
    *(uint4*)&tile[row][part * 16]     = ((const uint4*)v)[0];
    *(uint4*)&tile[row][part * 16 + 8] = ((const uint4*)v)[1];
  }
  __syncthreads();
  {
    int c = t & 63, rq = t >> 6;
    u16 v[16];
#pragma unroll
    for (int i = 0; i < 16; i++) v[i] = tile[rq * 16 + i][c];
    u16* dst = out + (size_t)(c0 + c) * R + r0 + rq * 16;
    ((uint4*)dst)[0] = ((const uint4*)v)[0];
    ((uint4*)dst)[1] = ((const uint4*)v)[1];
  }
}

__global__ __launch_bounds__(256) void transpose_cvt64(const float* __restrict__ in,
                                                       u16* __restrict__ out,
                                                       int R, int Cc) {
  __shared__ u16 tile[64][72];
  tcvt64_body(in, out, R, Cc, blockIdx.x * 64, blockIdx.y * 64, threadIdx.x, tile);
}

// ---- fused Wq/Wk/Wv transpose (one launch): grid.x slices select the matrix ----
__global__ __launch_bounds__(256) void transpose_wqkv(const float* __restrict__ Wq,
                                                      const float* __restrict__ Wk,
                                                      const float* __restrict__ Wv,
                                                      u16* __restrict__ out) {
  __shared__ u16 tile[64][72];
  int bx = blockIdx.x;
  const float* in;
  u16* dst;
  int Cc, c0;
  if (bx < 32)      { in = Wq; dst = out;                        Cc = 2048; c0 = bx * 64; }
  else if (bx < 40) { in = Wk; dst = out + (size_t)2048 * 2048;  Cc = 512;  c0 = (bx - 32) * 64; }
  else              { in = Wv; dst = out + (size_t)2560 * 2048;  Cc = 512;  c0 = (bx - 40) * 64; }
  tcvt64_body(in, dst, 2048, Cc, c0, blockIdx.y * 64, threadIdx.x, tile);
}

// ---- 64x64 vectorized bf16 transpose with input row-stride (V slice) ----
__global__ __launch_bounds__(256) void transpose_sl64(const u16* __restrict__ in, int ldin,
                                                      u16* __restrict__ out,
                                                      int R, int Cc) {
  __shared__ u16 tile[64][72];
  int c0 = blockIdx.x * 64, r0 = blockIdx.y * 64;
  int t = threadIdx.x;
  {
    int row = t >> 2, part = t & 3;
    const u16* src = in + (size_t)(r0 + row) * ldin + c0 + part * 16;
    uint4 a = ((const uint4*)src)[0];
    uint4 b = ((const uint4*)src)[1];
    *(uint4*)&tile[row][part * 16]     = a;
    *(uint4*)&tile[row][part * 16 + 8] = b;
  }
  __syncthreads();
  {
    int c = t & 63, rq = t >> 6;
    u16 v[16];
#pragma unroll
    for (int i = 0; i < 16; i++) v[i] = tile[rq * 16 + i][c];
    u16* dst = out + (size_t)(c0 + c) * R + r0 + rq * 16;
    ((uint4*)dst)[0] = ((const uint4*)v)[0];
    ((uint4*)dst)[1] = ((const uint4*)v)[1];
  }
}

// ------------- RoPE, vectorized + fused Q/K passes in one launch -------------
// Q slice (idx < NQ): scale (1/sqrt(64))*log2(e) folded in. K slice: scale 1.
DEVI void rope_body(u16* X, int h4shift, float scale, int idx) {
  int hq   = idx & ((1 << h4shift) - 1);
  int row  = idx >> h4shift;
  int head = hq >> 2;
  int d0   = (hq & 3) * 8;
  int tpos = row & 2047;
  size_t base = (size_t)row * 3072 + head * 64 + d0;
  uint4 lo = *(const uint4*)(X + base);
  uint4 hi = *(const uint4*)(X + base + 32);
  const u16* lp = (const u16*)&lo;
  const u16* hp = (const u16*)&hi;
  float ang = (float)tpos * exp2f(-(float)d0 * 0.59161152f);  // 500000^(-d/32)
  u16 o0[8], o1[8];
#pragma unroll
  for (int i = 0; i < 8; i++) {
    float s, c;
    __sincosf(ang, &s, &c);
    s *= scale; c *= scale;
    float x0 = bf2f(lp[i]);
    float x1 = bf2f(hp[i]);
    o0[i] = f2bf(x0 * c - x1 * s);
    o1[i] = f2bf(x1 * c + x0 * s);
    ang *= 0.6636011f;  // 2^(-0.59161152)
  }
  *(uint4*)(X + base)      = *(const uint4*)o0;
  *(uint4*)(X + base + 32) = *(const uint4*)o1;
}

__global__ __launch_bounds__(256) void rope_fused(u16* __restrict__ QKV) {
  const int NQ = 4096 * 128;                // Q: 4096 rows x 32 heads x 4 vec-chunks
  int idx = blockIdx.x * 256 + threadIdx.x;
  if (idx < NQ) rope_body(QKV, 7, 0.18033688f, idx);
  else          rope_body(QKV + 2048, 5, 1.0f, idx - NQ);
}

// ---- GEMM: C[M,N] = A[M,K] * Bt[N,K]^T, 128x128 tile, BK=32, 2-phase dbuf ----
DEVI void cstore(u16* C, size_t idx, float v)   { C[idx] = f2bf(v); }
DEVI void cstore(float* C, size_t idx, float v) { C[idx] = v; }

template <typename TO>
__global__ __launch_bounds__(256) void gemm128(const u16* __restrict__ A,
                                               const u16* __restrict__ Bt,
                                               TO* __restrict__ C,
                                               int M, int N, int K) {
  __shared__ u16 As[2 * 128 * 32];
  __shared__ u16 Bs[2 * 128 * 32];
  int tid = threadIdx.x, wid = tid >> 6, lane = tid & 63;
  int quad = lane >> 4, l15 = lane & 15;
  int m0 = blockIdx.y * 128, n0 = blockIdx.x * 128;
  int wm = (wid >> 1) * 64, wn = (wid & 1) * 64;

  int r0s = wid * 16 + (lane >> 2);
  int r1s = 64 + wid * 16 + (lane >> 2);
  int cblk = lane & 3;
  int cs0 = (cblk ^ ((r0s >> 1) & 3)) * 8;
  int cs1 = (cblk ^ ((r1s >> 1) & 3)) * 8;
  u16* lA0 = As + wid * 512 + lane * 8;
  u16* lA1 = As + (4 + wid) * 512 + lane * 8;
  u16* lB0 = Bs + wid * 512 + lane * 8;
  u16* lB1 = Bs + (4 + wid) * 512 + lane * 8;
  const u16* gA0 = A + (size_t)(m0 + r0s) * K + cs0;
  const u16* gA1 = A + (size_t)(m0 + r1s) * K + cs1;
  const u16* gB0 = Bt + (size_t)(n0 + r0s) * K + cs0;
  const u16* gB1 = Bt + (size_t)(n0 + r1s) * K + cs1;

  f32x4 acc[4][4];
  for (int i = 0; i < 4; i++)
    for (int j = 0; j < 4; j++) acc[i][j] = f32x4{0.f, 0.f, 0.f, 0.f};

  // prologue: stage K-step 0 into buf 0
  gload16(gA0, lA0);
  gload16(gA1, lA1);
  gload16(gB0, lB0);
  gload16(gB1, lB1);
  __builtin_amdgcn_s_waitcnt(0x0F70);  // vmcnt(0)
  __syncthreads();

  int cur = 0;
  for (int k0 = 0; k0 < K; k0 += 32) {
    int nb = cur ^ 1;
    if (k0 + 32 < K) {                 // prefetch next K-step into other buf
      gload16(gA0 + k0 + 32, lA0 + nb * 4096);
      gload16(gA1 + k0 + 32, lA1 + nb * 4096);
      gload16(gB0 + k0 + 32, lB0 + nb * 4096);
      gload16(gB1 + k0 + 32, lB1 + nb * 4096);
    }
    const u16* Ab = As + cur * 4096;
    const u16* Bb = Bs + cur * 4096;
    bf16x8 af[4], bf_[4];
    for (int mi = 0; mi < 4; mi++) {
      int row = wm + mi * 16 + l15;
      af[mi] = *(const bf16x8*)(Ab + row * 32 + ((quad ^ ((row >> 1) & 3)) * 8));
    }
    for (int ni = 0; ni < 4; ni++) {
      int row = wn + ni * 16 + l15;
      bf_[ni] = *(const bf16x8*)(Bb + row * 32 + ((quad ^ ((row >> 1) & 3)) * 8));
    }
    for (int mi = 0; mi < 4; mi++)
      for (int ni = 0; ni < 4; ni++)
        acc[mi][ni] = __builtin_amdgcn_mfma_f32_16x16x32_bf16(af[mi], bf_[ni], acc[mi][ni], 0, 0, 0);
    __builtin_amdgcn_s_waitcnt(0x0F70);  // vmcnt(0): prefetch landed
    __syncthreads();                     // one barrier per K-step
    cur = nb;
  }
  for (int mi = 0; mi < 4; mi++)
    for (int ni = 0; ni < 4; ni++)
      for (int r = 0; r < 4; r++) {
        int row = m0 + wm + mi * 16 + quad * 4 + r;
        int col = n0 + wn + ni * 16 + l15;
        cstore(C, (size_t)row * N + col, acc[mi][ni][r]);
      }
}

// ---------------- Flash attention v6: occupancy via un-pairing ----------------
// R6 post-mortem: zacc MFMA (+25% MFMA issue) cost more than the VALU it saved
// -> reverted to the R5-verified VALU zsum + epilogue shuffles (fzero seed kept).
// R6 counters: Occupancy 19%, VGPR 96, LDS 32KB -> GRID-limited (512 blocks =
// 2 waves/SIMD cap). v6: un-pair -> grid (16,64) = 1024 blocks, one q-strip per
// block, longest strips dispatched first (j = 15 - blockIdx.x). ~4 blocks/CU
// resident; imbalance absorbed by overlap instead of lockstep drain.
__global__ __launch_bounds__(256) void attn64(const u16* __restrict__ QKV,
                                              const u16* __restrict__ Vt,
                                              u16* __restrict__ Y) {
  __shared__ u16 Ks[2 * 64 * 64];   // 2 bufs, [key][d], granule-swizzled
  __shared__ u16 Vst[2 * 64 * 64];  // 2 bufs, [d][key], granule-swizzled

  int tid = threadIdx.x, wid = tid >> 6, lane = tid & 63;
  int l31 = lane & 31, hi = lane >> 5;
  int bh = blockIdx.y, b = bh >> 5, h = bh & 31, kvh = h >> 2;
  int j = 15 - blockIdx.x;                  // q-strip index; longest first

  // K staging (global_load_lds, linear dest + inverse-swizzled src)
  int kr  = wid * 8 + (lane >> 3);
  int kgn = lane & 7;
  const u16* gK0 = QKV + (size_t)(b * 2048 + kr) * 3072 + 2048 + kvh * 64
                 + ((kgn ^ (kr & 7)) * 8);
  u16* lK0 = Ks + wid * 512 + lane * 8;     // +buf*4096; +2048 for rows+32

  // V staging (reg-staged, swizzled ds_write)
  int vr = tid >> 3, vg = tid & 7;
  const u16* gV0 = Vt + (size_t)(kvh * 64 + vr) * 4096 + b * 2048 + vg * 8;
  u16* lV0 = Vst + vr * 64 + ((vg ^ (vr & 7)) * 8);  // +buf*4096; +2048 for d+32

  // persistent zero C-vector (MFMA chain seed; kills 16 v_mov per subtile)
  f32x16 fzero;
#pragma unroll
  for (int i = 0; i < 16; i++) fzero[i] = 0.f;

  int q0w = j * 128 + wid * 32;
  int qg  = q0w + l31;                      // this lane's q row

  // Q fragments (RoPE'd + scale-folded in place): Q[qg][dh*16 + hi*8 + i]
  bf16x8 qf[4];
  {
    const u16* qp = QKV + (size_t)(b * 2048 + qg) * 3072 + h * 64 + hi * 8;
#pragma unroll
    for (int dh = 0; dh < 4; dh++) qf[dh] = *(const bf16x8*)(qp + dh * 16);
  }

  f32x16 o0, o1;
#pragma unroll
  for (int i = 0; i < 16; i++) { o0[i] = 0.f; o1[i] = 0.f; }
  float zsum = 0.f;

  int nkt = 2 * (j + 1);                    // 64-key tiles covering 0..j*128+127

  // prologue: stage tile 0 into buf 0
  {
    uint4 va = *(const uint4*)(gV0);
    uint4 vb = *(const uint4*)(gV0 + 32 * 4096);
    gload16(gK0, lK0);
    gload16(gK0 + 32 * 3072, lK0 + 2048);
    __builtin_amdgcn_s_waitcnt(0x0F70);     // vmcnt(0)
    *(uint4*)(lV0)        = va;
    *(uint4*)(lV0 + 2048) = vb;
  }
  __syncthreads();

  int cur = 0;
  for (int kt = 0; kt < nkt; kt++) {
    int kbase = kt * 64;
    int nxt = cur ^ 1;
    bool more = (kt + 1 < nkt);
    uint4 va, vb;
    if (more) {                             // issue next tile's loads early
      size_t ko = (size_t)(kbase + 64);
      va = *(const uint4*)(gV0 + ko);
      vb = *(const uint4*)(gV0 + 32 * 4096 + ko);
      gload16(gK0 + ko * 3072, lK0 + nxt * 4096);
      gload16(gK0 + ko * 3072 + 32 * 3072, lK0 + nxt * 4096 + 2048);
    }

    const u16* Kb = Ks + cur * 4096;
    const u16* Vb = Vst + cur * 4096;
#pragma unroll
    for (int sub = 0; sub < 2; sub++) {
      int kb = kbase + sub * 32;
      if (kb > q0w) break;                  // wave-uniform causal skip

      // S^T[key][q] over keys kb..kb+31; chain seeded from fzero (no movs)
      bf16x8 kf0 = *(const bf16x8*)(Kb + (sub * 32 + l31) * 64 + ((hi ^ (l31 & 7)) * 8));
      f32x16 s = __builtin_amdgcn_mfma_f32_32x32x16_bf16(kf0, qf[0], fzero, 0, 0, 0);
#pragma unroll
      for (int dh = 1; dh < 4; dh++) {
        int g = (dh * 2 + hi) ^ (l31 & 7);
        bf16x8 kf = *(const bf16x8*)(Kb + (sub * 32 + l31) * 64 + g * 8);
        s = __builtin_amdgcn_mfma_f32_32x32x16_bf16(kf, qf[dh], s, 0, 0, 0);
      }

      float pb[16];
      if (kb < q0w) {                       // full subtile: no mask needed
#pragma unroll
        for (int r = 0; r < 16; r++) {
          float pv = exp2f(s[r]);
          zsum += pv;
          pb[r] = pv;
        }
      } else {                              // diagonal subtile (kb == q0w)
#pragma unroll
        for (int r = 0; r < 16; r++) {
          int key = kb + (r & 3) + 8 * (r >> 2) + 4 * hi;
          float pv = (key <= qg) ? exp2f(s[r]) : 0.f;
          zsum += pv;
          pb[r] = pv;
        }
      }

      // P -> PV A-fragment: cvt_pk + permlane32_swap (verified round 3)
#pragma unroll
      for (int kk = 0; kk < 2; kk++) {
        const float* pp = pb + kk * 8;
        u32 a01 = pkbf(pp[0], pp[1]);
        u32 a23 = pkbf(pp[2], pp[3]);
        u32 a45 = pkbf(pp[4], pp[5]);
        u32 a67 = pkbf(pp[6], pp[7]);
        asm volatile("v_permlane32_swap_b32 %0, %1" : "+v"(a01), "+v"(a45));
        asm volatile("v_permlane32_swap_b32 %0, %1" : "+v"(a23), "+v"(a67));
        union { u32 w[4]; bf16x8 v; } pf;
        pf.w[0] = a01; pf.w[1] = a23; pf.w[2] = a45; pf.w[3] = a67;
        int kgr = sub * 4 + kk * 2 + hi;    // key granule within 64-key tile
        const u16* vp = Vb + l31 * 64 + ((kgr ^ (l31 & 7)) * 8);
        bf16x8 v0 = *(const bf16x8*)(vp);
        bf16x8 v1 = *(const bf16x8*)(vp + 2048);   // d+32 rows
        o0 = __builtin_amdgcn_mfma_f32_32x32x16_bf16(pf.v, v0, o0, 0, 0, 0);
        o1 = __builtin_amdgcn_mfma_f32_32x32x16_bf16(pf.v, v1, o1, 0, 0, 0);
      }
    }

    if (more) {
      __builtin_amdgcn_s_waitcnt(0x0F70);   // vmcnt(0): K in LDS, V in regs
      *(uint4*)(lV0 + nxt * 4096)        = va;
      *(uint4*)(lV0 + nxt * 4096 + 2048) = vb;
    }
    __syncthreads();                        // one barrier per 64-key tile
    cur = nxt;
  }

  // row sums: lane and lane^32 hold complementary key-halves of q = l31
  float zf = zsum + __shfl_xor(zsum, 32);

  // write out: C rows are q = (r&3)+8*(r>>2)+4*hi, cols d = half*32 + l31
#pragma unroll
  for (int r = 0; r < 16; r++) {
    int qr = (r & 3) + 8 * (r >> 2) + 4 * hi;  // local q row 0..31
    float zr = __shfl(zf, qr, 64);
    float inv = 1.f / zr;
    size_t row = (size_t)(b * 2048 + q0w + qr);
    Y[row * 2048 + h * 64 + l31]      = f2bf(o0[r] * inv);
    Y[row * 2048 + h * 64 + 32 + l31] = f2bf(o1[r] * inv);
  }
}

extern "C" void kernel_launch(void* const* d_in, const int* in_sizes, int n_in,
                              void* d_out, int out_size, void* d_ws, size_t ws_size,
                              hipStream_t stream) {
  const float* x  = (const float*)d_in[0];  // [4096][2048] fp32
  const float* Wq = (const float*)d_in[1];  // [2048][2048]
  const float* Wk = (const float*)d_in[2];  // [2048][512]
  const float* Wv = (const float*)d_in[3];  // [2048][512]
  const float* Wo = (const float*)d_in[4];  // [2048][2048]
  float* outp = (float*)d_out;              // fp32 out

  // workspace (u16 units), ~59 MB peak
  u16* xb    = (u16*)d_ws;             // [4096][2048]   8388608
  u16* WqkvT = xb + 8388608;           // [3072][2048]   6291456
  u16* QKV   = WqkvT + 6291456;        // [4096][3072]  12582912
  u16* Vt    = QKV + 12582912;         // [512][4096]    2097152
  u16* Yb    = xb;                     // reuse (xb dead after QKV gemm)
  u16* WoT   = WqkvT;                  // reuse (WqkvT dead after QKV gemm)

  // x -> bf16
  cvt_bf16_f32<<<4096, 256, 0, stream>>>(x, xb, 1048576);

  // weights -> transposed bf16, stacked [Wq^T; Wk^T; Wv^T] (one launch)
  transpose_wqkv<<<dim3(48, 32), 256, 0, stream>>>(Wq, Wk, Wv, WqkvT);

  // fused QKV projection: [4096,2048] x [2048,3072] -> [4096,3072]
  gemm128<u16><<<dim3(24, 32), 256, 0, stream>>>(xb, WqkvT, QKV, 4096, 3072, 2048);

  // RoPE (vectorized, Q+K fused; Q pass folds (1/sqrt(64))*log2(e))
  rope_fused<<<2560, 256, 0, stream>>>(QKV);

  // V slice -> V^T
  transpose_sl64<<<dim3(8, 64), 256, 0, stream>>>(QKV + 2560, 3072, Vt, 4096, 512);

  // attention (KVBLK=64, un-paired strips, longest-first) -> Yb
  attn64<<<dim3(16, 64), 256, 0, stream>>>(QKV, Vt, Yb);

  // Wo -> WoT, output projection -> fp32 d_out
  transpose_cvt64<<<dim3(32, 32), 256, 0, stream>>>(Wo, WoT, 2048, 2048);
  gemm128<float><<<dim3(16, 32), 256, 0, stream>>>(Yb, WoT, outp, 4096, 2048, 2048);
}

// Round 8
// 310.491 us; speedup vs baseline: 1.1743x; 1.1743x over previous
//
#include <hip/hip_runtime.h>

using u16 = unsigned short;
using u32 = unsigned int;

typedef __attribute__((ext_vector_type(8))) __bf16 bf16x8;
typedef __attribute__((ext_vector_type(4))) float f32x4;
typedef __attribute__((ext_vector_type(16))) float f32x16;

#define DEVI __device__ __forceinline__

DEVI float bf2f(u16 u) {
  union { u32 i; float f; } v; v.i = ((u32)u) << 16; return v.f;
}
DEVI u16 f2bf(float f) {
  union { float f; u32 u; } v; v.f = f;
  u32 u = v.u;
  u32 r = (u + 0x7fffu + ((u >> 16) & 1u)) >> 16;
  return (u16)r;
}
// pack two f32 -> one u32 of 2x bf16 (compiler emits v_cvt_pk_bf16_f32)
DEVI u32 pkbf(float a, float b) {
  union { __bf16 h[2]; u32 u; } t;
  t.h[0] = (__bf16)a; t.h[1] = (__bf16)b;
  return t.u;
}

// async global->LDS, 16B per lane. LDS dest = wave-uniform base + lane*16.
DEVI void gload16(const u16* g, u16* l) {
  __builtin_amdgcn_global_load_lds(
      (const __attribute__((address_space(1))) void*)g,
      (__attribute__((address_space(3))) void*)l, 16, 0, 0);
}

// ---------------- cvt x: fp32 -> bf16, 8 elems/thread ----------------
__global__ __launch_bounds__(256) void cvt_bf16_f32(const float* __restrict__ in,
                                                    u16* __restrict__ out, int n8) {
  int i = blockIdx.x * 256 + threadIdx.x;
  if (i >= n8) return;
  const float4* fin = (const float4*)in;
  float4 a = fin[i * 2], b = fin[i * 2 + 1];
  u16 o[8] = {f2bf(a.x), f2bf(a.y), f2bf(a.z), f2bf(a.w),
              f2bf(b.x), f2bf(b.y), f2bf(b.z), f2bf(b.w)};
  ((uint4*)out)[i] = *(const uint4*)o;
}

// ------- 64x64 transpose+convert body: in[R][Cc] f32 -> out[Cc][R] bf16 -------
DEVI void tcvt64_body(const float* in, u16* out, int R, int Cc, int c0, int r0, int t,
                      u16 (*tile)[72]) {
  {
    int row = t >> 2, part = t & 3;
    const float* src = in + (size_t)(r0 + row) * Cc + c0 + part * 16;
    float4 f0 = ((const float4*)src)[0];
    float4 f1 = ((const float4*)src)[1];
    float4 f2 = ((const float4*)src)[2];
    float4 f3 = ((const float4*)src)[3];
    u16 v[16] = {f2bf(f0.x), f2bf(f0.y), f2bf(f0.z), f2bf(f0.w),
                 f2bf(f1.x), f2bf(f1.y), f2bf(f1.z), f2bf(f1.w),
                 f2bf(f2.x), f2bf(f2.y), f2bf(f2.z), f2bf(f2.w),
                 f2bf(f3.x), f2bf(f3.y), f2bf(f3.z), f2bf(f3.w)};
    *(uint4*)&tile[row][part * 16]     = ((const uint4*)v)[0];
    *(uint4*)&tile[row][part * 16 + 8] = ((const uint4*)v)[1];
  }
  __syncthreads();
  {
    int c = t & 63, rq = t >> 6;
    u16 v[16];
#pragma unroll
    for (int i = 0; i < 16; i++) v[i] = tile[rq * 16 + i][c];
    u16* dst = out + (size_t)(c0 + c) * R + r0 + rq * 16;
    ((uint4*)dst)[0] = ((const uint4*)v)[0];
    ((uint4*)dst)[1] = ((const uint4*)v)[1];
  }
}

__global__ __launch_bounds__(256) void transpose_cvt64(const float* __restrict__ in,
                                                       u16* __restrict__ out,
                                                       int R, int Cc) {
  __shared__ u16 tile[64][72];
  tcvt64_body(in, out, R, Cc, blockIdx.x * 64, blockIdx.y * 64, threadIdx.x, tile);
}

// ---- fused Wq/Wk/Wv transpose (one launch): grid.x slices select the matrix ----
__global__ __launch_bounds__(256) void transpose_wqkv(const float* __restrict__ Wq,
                                                      const float* __restrict__ Wk,
                                                      const float* __restrict__ Wv,
                                                      u16* __restrict__ out) {
  __shared__ u16 tile[64][72];
  int bx = blockIdx.x;
  const float* in;
  u16* dst;
  int Cc, c0;
  if (bx < 32)      { in = Wq; dst = out;                        Cc = 2048; c0 = bx * 64; }
  else if (bx < 40) { in = Wk; dst = out + (size_t)2048 * 2048;  Cc = 512;  c0 = (bx - 32) * 64; }
  else              { in = Wv; dst = out + (size_t)2560 * 2048;  Cc = 512;  c0 = (bx - 40) * 64; }
  tcvt64_body(in, dst, 2048, Cc, c0, blockIdx.y * 64, threadIdx.x, tile);
}

// ---- 64x64 vectorized bf16 transpose with input row-stride (V slice) ----
__global__ __launch_bounds__(256) void transpose_sl64(const u16* __restrict__ in, int ldin,
                                                      u16* __restrict__ out,
                                                      int R, int Cc) {
  __shared__ u16 tile[64][72];
  int c0 = blockIdx.x * 64, r0 = blockIdx.y * 64;
  int t = threadIdx.x;
  {
    int row = t >> 2, part = t & 3;
    const u16* src = in + (size_t)(r0 + row) * ldin + c0 + part * 16;
    uint4 a = ((const uint4*)src)[0];
    uint4 b = ((const uint4*)src)[1];
    *(uint4*)&tile[row][part * 16]     = a;
    *(uint4*)&tile[row][part * 16 + 8] = b;
  }
  __syncthreads();
  {
    int c = t & 63, rq = t >> 6;
    u16 v[16];
#pragma unroll
    for (int i = 0; i < 16; i++) v[i] = tile[rq * 16 + i][c];
    u16* dst = out + (size_t)(c0 + c) * R + r0 + rq * 16;
    ((uint4*)dst)[0] = ((const uint4*)v)[0];
    ((uint4*)dst)[1] = ((const uint4*)v)[1];
  }
}

// ---- GEMM: C[M,N] = A[M,K] * Bt[N,K]^T, 128x128 tile, BK=32, 2-phase dbuf ----
// R8: (a) T1 XCD-aware block swizzle (bijective: nwg%8==0 for both calls);
//     (b) ROPE template param: QKV instantiation rotates Q/K pairs (d, d+32)
//         in the f32 accumulator before the bf16 store (head = the wave's
//         64-col block; acc[mi][ni] pairs with acc[mi][ni+2]), folding the
//         softmax scale into Q. Deletes the standalone rope kernel + a 20MB
//         QKV read/write round trip, and drops one bf16 rounding.
DEVI void cstore(u16* C, size_t idx, float v)   { C[idx] = f2bf(v); }
DEVI void cstore(float* C, size_t idx, float v) { C[idx] = v; }

template <typename TO, bool ROPE>
__global__ __launch_bounds__(256) void gemm128(const u16* __restrict__ A,
                                               const u16* __restrict__ Bt,
                                               TO* __restrict__ C,
                                               int M, int N, int K) {
  __shared__ u16 As[2 * 128 * 32];
  __shared__ u16 Bs[2 * 128 * 32];
  int tid = threadIdx.x, wid = tid >> 6, lane = tid & 63;
  int quad = lane >> 4, l15 = lane & 15;

  // T1 XCD swizzle: contiguous grid chunk per XCD (requires nwg % 8 == 0)
  int nwg = gridDim.x * gridDim.y;
  int bid = blockIdx.y * gridDim.x + blockIdx.x;
  int swz = (bid & 7) * (nwg >> 3) + (bid >> 3);
  int bx = swz % gridDim.x, by = swz / gridDim.x;
  int m0 = by * 128, n0 = bx * 128;
  int wm = (wid >> 1) * 64, wn = (wid & 1) * 64;

  int r0s = wid * 16 + (lane >> 2);
  int r1s = 64 + wid * 16 + (lane >> 2);
  int cblk = lane & 3;
  int cs0 = (cblk ^ ((r0s >> 1) & 3)) * 8;
  int cs1 = (cblk ^ ((r1s >> 1) & 3)) * 8;
  u16* lA0 = As + wid * 512 + lane * 8;
  u16* lA1 = As + (4 + wid) * 512 + lane * 8;
  u16* lB0 = Bs + wid * 512 + lane * 8;
  u16* lB1 = Bs + (4 + wid) * 512 + lane * 8;
  const u16* gA0 = A + (size_t)(m0 + r0s) * K + cs0;
  const u16* gA1 = A + (size_t)(m0 + r1s) * K + cs1;
  const u16* gB0 = Bt + (size_t)(n0 + r0s) * K + cs0;
  const u16* gB1 = Bt + (size_t)(n0 + r1s) * K + cs1;

  f32x4 acc[4][4];
  for (int i = 0; i < 4; i++)
    for (int j = 0; j < 4; j++) acc[i][j] = f32x4{0.f, 0.f, 0.f, 0.f};

  // prologue: stage K-step 0 into buf 0
  gload16(gA0, lA0);
  gload16(gA1, lA1);
  gload16(gB0, lB0);
  gload16(gB1, lB1);
  __builtin_amdgcn_s_waitcnt(0x0F70);  // vmcnt(0)
  __syncthreads();

  int cur = 0;
  for (int k0 = 0; k0 < K; k0 += 32) {
    int nb = cur ^ 1;
    if (k0 + 32 < K) {                 // prefetch next K-step into other buf
      gload16(gA0 + k0 + 32, lA0 + nb * 4096);
      gload16(gA1 + k0 + 32, lA1 + nb * 4096);
      gload16(gB0 + k0 + 32, lB0 + nb * 4096);
      gload16(gB1 + k0 + 32, lB1 + nb * 4096);
    }
    const u16* Ab = As + cur * 4096;
    const u16* Bb = Bs + cur * 4096;
    bf16x8 af[4], bf_[4];
    for (int mi = 0; mi < 4; mi++) {
      int row = wm + mi * 16 + l15;
      af[mi] = *(const bf16x8*)(Ab + row * 32 + ((quad ^ ((row >> 1) & 3)) * 8));
    }
    for (int ni = 0; ni < 4; ni++) {
      int row = wn + ni * 16 + l15;
      bf_[ni] = *(const bf16x8*)(Bb + row * 32 + ((quad ^ ((row >> 1) & 3)) * 8));
    }
    for (int mi = 0; mi < 4; mi++)
      for (int ni = 0; ni < 4; ni++)
        acc[mi][ni] = __builtin_amdgcn_mfma_f32_16x16x32_bf16(af[mi], bf_[ni], acc[mi][ni], 0, 0, 0);
    __builtin_amdgcn_s_waitcnt(0x0F70);  // vmcnt(0): prefetch landed
    __syncthreads();                     // one barrier per K-step
    cur = nb;
  }

  if (ROPE) {
    // rotate (d, d+32) pairs for Q (cols<2048, scale folded) and K (2048..2560)
#pragma unroll
    for (int ni = 0; ni < 2; ni++) {
      int nc = n0 + wn + ni * 16;            // block-uniform
      if (nc < 2560) {
        float scale = (nc < 2048) ? 0.18033688f : 1.0f;  // (1/8)*log2(e) for Q
        float inv = exp2f(-(float)(ni * 16 + l15) * 0.59161152f);  // theta^-(d/32)
#pragma unroll
        for (int mi = 0; mi < 4; mi++)
#pragma unroll
          for (int r = 0; r < 4; r++) {
            int t = (m0 + wm + mi * 16 + quad * 4 + r) & 2047;
            float sn, cs;
            __sincosf((float)t * inv, &sn, &cs);
            float xl = acc[mi][ni][r], xh = acc[mi][ni + 2][r];
            acc[mi][ni][r]     = (xl * cs - xh * sn) * scale;
            acc[mi][ni + 2][r] = (xh * cs + xl * sn) * scale;
          }
      }
    }
  }

  for (int mi = 0; mi < 4; mi++)
    for (int ni = 0; ni < 4; ni++)
      for (int r = 0; r < 4; r++) {
        int row = m0 + wm + mi * 16 + quad * 4 + r;
        int col = n0 + wn + ni * 16 + l15;
        cstore(C, (size_t)row * N + col, acc[mi][ni][r]);
      }
}

// ---------------- Flash attention: R5-verbatim (proven 89.4 us) ----------------
// KVBLK=64, paired strips (j, 15-j) -> 512 uniform blocks of 34 tiles.
// R7 post-mortem: un-pairing created a 64-block drain tail (125 us) -> reverted.
// R6 post-mortem: zacc-MFMA cost > VALU saved -> reverted to VALU zsum.
__global__ __launch_bounds__(256) void attn64(const u16* __restrict__ QKV,
                                              const u16* __restrict__ Vt,
                                              u16* __restrict__ Y) {
  __shared__ u16 Ks[2 * 64 * 64];   // 2 bufs, [key][d], granule-swizzled
  __shared__ u16 Vst[2 * 64 * 64];  // 2 bufs, [d][key], granule-swizzled

  int tid = threadIdx.x, wid = tid >> 6, lane = tid & 63;
  int l31 = lane & 31, hi = lane >> 5;
  int bh = blockIdx.y, b = bh >> 5, h = bh & 31, kvh = h >> 2;
  int p = blockIdx.x;                       // pair index 0..7

  // K staging (global_load_lds, linear dest + inverse-swizzled src)
  int kr  = wid * 8 + (lane >> 3);
  int kgn = lane & 7;
  const u16* gK0 = QKV + (size_t)(b * 2048 + kr) * 3072 + 2048 + kvh * 64
                 + ((kgn ^ (kr & 7)) * 8);
  u16* lK0 = Ks + wid * 512 + lane * 8;     // +buf*4096; +2048 for rows+32

  // V staging (reg-staged, swizzled ds_write)
  int vr = tid >> 3, vg = tid & 7;
  const u16* gV0 = Vt + (size_t)(kvh * 64 + vr) * 4096 + b * 2048 + vg * 8;
  u16* lV0 = Vst + vr * 64 + ((vg ^ (vr & 7)) * 8);  // +buf*4096; +2048 for d+32

  for (int pass = 0; pass < 2; pass++) {
    int j   = pass ? (15 - p) : p;          // q-strip index 0..15
    int q0w = j * 128 + wid * 32;
    int qg  = q0w + l31;                    // this lane's q row

    // Q fragments (RoPE'd + scale-folded by the QKV gemm epilogue)
    bf16x8 qf[4];
    {
      const u16* qp = QKV + (size_t)(b * 2048 + qg) * 3072 + h * 64 + hi * 8;
#pragma unroll
      for (int dh = 0; dh < 4; dh++) qf[dh] = *(const bf16x8*)(qp + dh * 16);
    }

    f32x16 o0, o1;
#pragma unroll
    for (int i = 0; i < 16; i++) { o0[i] = 0.f; o1[i] = 0.f; }
    float zsum = 0.f;

    int nkt = 2 * (j + 1);                  // 64-key tiles covering 0..j*128+127

    // prologue: stage tile 0 into buf 0
    {
      uint4 va = *(const uint4*)(gV0);
      uint4 vb = *(const uint4*)(gV0 + 32 * 4096);
      gload16(gK0, lK0);
      gload16(gK0 + 32 * 3072, lK0 + 2048);
      __builtin_amdgcn_s_waitcnt(0x0F70);   // vmcnt(0)
      *(uint4*)(lV0)        = va;
      *(uint4*)(lV0 + 2048) = vb;
    }
    __syncthreads();

    int cur = 0;
    for (int kt = 0; kt < nkt; kt++) {
      int kbase = kt * 64;
      int nxt = cur ^ 1;
      bool more = (kt + 1 < nkt);
      uint4 va, vb;
      if (more) {                           // issue next tile's loads early
        size_t ko = (size_t)(kbase + 64);
        va = *(const uint4*)(gV0 + ko);
        vb = *(const uint4*)(gV0 + 32 * 4096 + ko);
        gload16(gK0 + ko * 3072, lK0 + nxt * 4096);
        gload16(gK0 + ko * 3072 + 32 * 3072, lK0 + nxt * 4096 + 2048);
      }

      const u16* Kb = Ks + cur * 4096;
      const u16* Vb = Vst + cur * 4096;
#pragma unroll
      for (int sub = 0; sub < 2; sub++) {
        int kb = kbase + sub * 32;
        if (kb > q0w) break;                // wave-uniform causal skip

        // S^T[key][q] over keys kb..kb+31 (scale pre-folded into Q)
        f32x16 s;
#pragma unroll
        for (int i = 0; i < 16; i++) s[i] = 0.f;
#pragma unroll
        for (int dh = 0; dh < 4; dh++) {
          int g = (dh * 2 + hi) ^ (l31 & 7);
          bf16x8 kf = *(const bf16x8*)(Kb + (sub * 32 + l31) * 64 + g * 8);
          s = __builtin_amdgcn_mfma_f32_32x32x16_bf16(kf, qf[dh], s, 0, 0, 0);
        }

        float pb[16];
        if (kb < q0w) {                     // full subtile: no mask needed
#pragma unroll
          for (int r = 0; r < 16; r++) {
            float pv = exp2f(s[r]);
            zsum += pv;
            pb[r] = pv;
          }
        } else {                            // diagonal subtile (kb == q0w)
#pragma unroll
          for (int r = 0; r < 16; r++) {
            int key = kb + (r & 3) + 8 * (r >> 2) + 4 * hi;
            float pv = (key <= qg) ? exp2f(s[r]) : 0.f;
            zsum += pv;
            pb[r] = pv;
          }
        }

        // P -> PV A-fragment: cvt_pk + permlane32_swap (verified round 3)
#pragma unroll
        for (int kk = 0; kk < 2; kk++) {
          const float* pp = pb + kk * 8;
          u32 a01 = pkbf(pp[0], pp[1]);
          u32 a23 = pkbf(pp[2], pp[3]);
          u32 a45 = pkbf(pp[4], pp[5]);
          u32 a67 = pkbf(pp[6], pp[7]);
          asm volatile("v_permlane32_swap_b32 %0, %1" : "+v"(a01), "+v"(a45));
          asm volatile("v_permlane32_swap_b32 %0, %1" : "+v"(a23), "+v"(a67));
          union { u32 w[4]; bf16x8 v; } pf;
          pf.w[0] = a01; pf.w[1] = a23; pf.w[2] = a45; pf.w[3] = a67;
          int kgr = sub * 4 + kk * 2 + hi;  // key granule within 64-key tile
          const u16* vp = Vb + l31 * 64 + ((kgr ^ (l31 & 7)) * 8);
          bf16x8 v0 = *(const bf16x8*)(vp);
          bf16x8 v1 = *(const bf16x8*)(vp + 2048);   // d+32 rows
          o0 = __builtin_amdgcn_mfma_f32_32x32x16_bf16(pf.v, v0, o0, 0, 0, 0);
          o1 = __builtin_amdgcn_mfma_f32_32x32x16_bf16(pf.v, v1, o1, 0, 0, 0);
        }
      }

      if (more) {
        __builtin_amdgcn_s_waitcnt(0x0F70); // vmcnt(0): K in LDS, V in regs
        *(uint4*)(lV0 + nxt * 4096)        = va;
        *(uint4*)(lV0 + nxt * 4096 + 2048) = vb;
      }
      __syncthreads();                      // one barrier per 64-key tile
      cur = nxt;
    }

    // row sums: lane and lane^32 hold complementary key-halves of q = l31
    float zf = zsum + __shfl_xor(zsum, 32);

    // write out: C rows are q = (r&3)+8*(r>>2)+4*hi, cols d = half*32 + l31
#pragma unroll
    for (int r = 0; r < 16; r++) {
      int qr = (r & 3) + 8 * (r >> 2) + 4 * hi;  // local q row 0..31
      float zr = __shfl(zf, qr, 64);
      float inv = 1.f / zr;
      size_t row = (size_t)(b * 2048 + q0w + qr);
      Y[row * 2048 + h * 64 + l31]      = f2bf(o0[r] * inv);
      Y[row * 2048 + h * 64 + 32 + l31] = f2bf(o1[r] * inv);
    }
  }
}

extern "C" void kernel_launch(void* const* d_in, const int* in_sizes, int n_in,
                              void* d_out, int out_size, void* d_ws, size_t ws_size,
                              hipStream_t stream) {
  const float* x  = (const float*)d_in[0];  // [4096][2048] fp32
  const float* Wq = (const float*)d_in[1];  // [2048][2048]
  const float* Wk = (const float*)d_in[2];  // [2048][512]
  const float* Wv = (const float*)d_in[3];  // [2048][512]
  const float* Wo = (const float*)d_in[4];  // [2048][2048]
  float* outp = (float*)d_out;              // fp32 out

  // workspace (u16 units), ~59 MB peak
  u16* xb    = (u16*)d_ws;             // [4096][2048]   8388608
  u16* WqkvT = xb + 8388608;           // [3072][2048]   6291456
  u16* QKV   = WqkvT + 6291456;        // [4096][3072]  12582912
  u16* Vt    = QKV + 12582912;         // [512][4096]    2097152
  u16* Yb    = xb;                     // reuse (xb dead after QKV gemm)
  u16* WoT   = WqkvT;                  // reuse (WqkvT dead after QKV gemm)

  // x -> bf16
  cvt_bf16_f32<<<4096, 256, 0, stream>>>(x, xb, 1048576);

  // weights -> transposed bf16, stacked [Wq^T; Wk^T; Wv^T] (one launch)
  transpose_wqkv<<<dim3(48, 32), 256, 0, stream>>>(Wq, Wk, Wv, WqkvT);

  // fused QKV projection + RoPE(+scale fold) epilogue: [4096,2048]x[2048,3072]
  gemm128<u16, true><<<dim3(24, 32), 256, 0, stream>>>(xb, WqkvT, QKV, 4096, 3072, 2048);

  // V slice -> V^T
  transpose_sl64<<<dim3(8, 64), 256, 0, stream>>>(QKV + 2560, 3072, Vt, 4096, 512);

  // attention (R5-verbatim: KVBLK=64, paired strips) -> Yb
  attn64<<<dim3(8, 64), 256, 0, stream>>>(QKV, Vt, Yb);

  // Wo -> WoT, output projection -> fp32 d_out
  transpose_cvt64<<<dim3(32, 32), 256, 0, stream>>>(Wo, WoT, 2048, 2048);
  gemm128<float, false><<<dim3(16, 32), 256, 0, stream>>>(Yb, WoT, outp, 4096, 2048, 2048);
}

// Round 9
// 309.297 us; speedup vs baseline: 1.1788x; 1.0039x over previous
//
#include <hip/hip_runtime.h>

using u16 = unsigned short;
using u32 = unsigned int;

typedef __attribute__((ext_vector_type(8))) __bf16 bf16x8;
typedef __attribute__((ext_vector_type(4))) float f32x4;
typedef __attribute__((ext_vector_type(16))) float f32x16;

#define DEVI __device__ __forceinline__

DEVI float bf2f(u16 u) {
  union { u32 i; float f; } v; v.i = ((u32)u) << 16; return v.f;
}
DEVI u16 f2bf(float f) {
  union { float f; u32 u; } v; v.f = f;
  u32 u = v.u;
  u32 r = (u + 0x7fffu + ((u >> 16) & 1u)) >> 16;
  return (u16)r;
}
// pack two f32 -> one u32 of 2x bf16 (compiler emits v_cvt_pk_bf16_f32)
DEVI u32 pkbf(float a, float b) {
  union { __bf16 h[2]; u32 u; } t;
  t.h[0] = (__bf16)a; t.h[1] = (__bf16)b;
  return t.u;
}

// async global->LDS, 16B per lane. LDS dest = wave-uniform base + lane*16.
DEVI void gload16(const u16* g, u16* l) {
  __builtin_amdgcn_global_load_lds(
      (const __attribute__((address_space(1))) void*)g,
      (__attribute__((address_space(3))) void*)l, 16, 0, 0);
}

// P-row (16 f32) -> PV A-fragment via cvt_pk + permlane32_swap (verified R3-R8)
DEVI bf16x8 packP(const float* pp) {
  u32 a01 = pkbf(pp[0], pp[1]);
  u32 a23 = pkbf(pp[2], pp[3]);
  u32 a45 = pkbf(pp[4], pp[5]);
  u32 a67 = pkbf(pp[6], pp[7]);
  asm volatile("v_permlane32_swap_b32 %0, %1" : "+v"(a01), "+v"(a45));
  asm volatile("v_permlane32_swap_b32 %0, %1" : "+v"(a23), "+v"(a67));
  union { u32 w[4]; bf16x8 v; } pf;
  pf.w[0] = a01; pf.w[1] = a23; pf.w[2] = a45; pf.w[3] = a67;
  return pf.v;
}

// ---------------- cvt x: fp32 -> bf16, 8 elems/thread ----------------
__global__ __launch_bounds__(256) void cvt_bf16_f32(const float* __restrict__ in,
                                                    u16* __restrict__ out, int n8) {
  int i = blockIdx.x * 256 + threadIdx.x;
  if (i >= n8) return;
  const float4* fin = (const float4*)in;
  float4 a = fin[i * 2], b = fin[i * 2 + 1];
  u16 o[8] = {f2bf(a.x), f2bf(a.y), f2bf(a.z), f2bf(a.w),
              f2bf(b.x), f2bf(b.y), f2bf(b.z), f2bf(b.w)};
  ((uint4*)out)[i] = *(const uint4*)o;
}

// ------- 64x64 transpose+convert body: in[R][Cc] f32 -> out[Cc][R] bf16 -------
DEVI void tcvt64_body(const float* in, u16* out, int R, int Cc, int c0, int r0, int t,
                      u16 (*tile)[72]) {
  {
    int row = t >> 2, part = t & 3;
    const float* src = in + (size_t)(r0 + row) * Cc + c0 + part * 16;
    float4 f0 = ((const float4*)src)[0];
    float4 f1 = ((const float4*)src)[1];
    float4 f2 = ((const float4*)src)[2];
    float4 f3 = ((const float4*)src)[3];
    u16 v[16] = {f2bf(f0.x), f2bf(f0.y), f2bf(f0.z), f2bf(f0.w),
                 f2bf(f1.x), f2bf(f1.y), f2bf(f1.z), f2bf(f1.w),
                 f2bf(f2.x), f2bf(f2.y), f2bf(f2.z), f2bf(f2.w),
                 f2bf(f3.x), f2bf(f3.y), f2bf(f3.z), f2bf(f3.w)};
    *(uint4*)&tile[row][part * 16]     = ((const uint4*)v)[0];
    *(uint4*)&tile[row][part * 16 + 8] = ((const uint4*)v)[1];
  }
  __syncthreads();
  {
    int c = t & 63, rq = t >> 6;
    u16 v[16];
#pragma unroll
    for (int i = 0; i < 16; i++) v[i] = tile[rq * 16 + i][c];
    u16* dst = out + (size_t)(c0 + c) * R + r0 + rq * 16;
    ((uint4*)dst)[0] = ((const uint4*)v)[0];
    ((uint4*)dst)[1] = ((const uint4*)v)[1];
  }
}

__global__ __launch_bounds__(256) void transpose_cvt64(const float* __restrict__ in,
                                                       u16* __restrict__ out,
                                                       int R, int Cc) {
  __shared__ u16 tile[64][72];
  tcvt64_body(in, out, R, Cc, blockIdx.x * 64, blockIdx.y * 64, threadIdx.x, tile);
}

// ---- fused Wq/Wk/Wv transpose (one launch): grid.x slices select the matrix ----
__global__ __launch_bounds__(256) void transpose_wqkv(const float* __restrict__ Wq,
                                                      const float* __restrict__ Wk,
                                                      const float* __restrict__ Wv,
                                                      u16* __restrict__ out) {
  __shared__ u16 tile[64][72];
  int bx = blockIdx.x;
  const float* in;
  u16* dst;
  int Cc, c0;
  if (bx < 32)      { in = Wq; dst = out;                        Cc = 2048; c0 = bx * 64; }
  else if (bx < 40) { in = Wk; dst = out + (size_t)2048 * 2048;  Cc = 512;  c0 = (bx - 32) * 64; }
  else              { in = Wv; dst = out + (size_t)2560 * 2048;  Cc = 512;  c0 = (bx - 40) * 64; }
  tcvt64_body(in, dst, 2048, Cc, c0, blockIdx.y * 64, threadIdx.x, tile);
}

// ---- 64x64 vectorized bf16 transpose with input row-stride (V slice) ----
__global__ __launch_bounds__(256) void transpose_sl64(const u16* __restrict__ in, int ldin,
                                                      u16* __restrict__ out,
                                                      int R, int Cc) {
  __shared__ u16 tile[64][72];
  int c0 = blockIdx.x * 64, r0 = blockIdx.y * 64;
  int t = threadIdx.x;
  {
    int row = t >> 2, part = t & 3;
    const u16* src = in + (size_t)(r0 + row) * ldin + c0 + part * 16;
    uint4 a = ((const uint4*)src)[0];
    uint4 b = ((const uint4*)src)[1];
    *(uint4*)&tile[row][part * 16]     = a;
    *(uint4*)&tile[row][part * 16 + 8] = b;
  }
  __syncthreads();
  {
    int c = t & 63, rq = t >> 6;
    u16 v[16];
#pragma unroll
    for (int i = 0; i < 16; i++) v[i] = tile[rq * 16 + i][c];
    u16* dst = out + (size_t)(c0 + c) * R + r0 + rq * 16;
    ((uint4*)dst)[0] = ((const uint4*)v)[0];
    ((uint4*)dst)[1] = ((const uint4*)v)[1];
  }
}

// ---- GEMM: C[M,N] = A[M,K] * Bt[N,K]^T, 128x128 tile, BK=32, 2-phase dbuf ----
// R8-verified: T1 XCD swizzle (bijective) + ROPE epilogue on the QKV call
// (rotates (d,d+32) in f32 acc, folds softmax scale into Q). Frozen this round.
DEVI void cstore(u16* C, size_t idx, float v)   { C[idx] = f2bf(v); }
DEVI void cstore(float* C, size_t idx, float v) { C[idx] = v; }

template <typename TO, bool ROPE>
__global__ __launch_bounds__(256) void gemm128(const u16* __restrict__ A,
                                               const u16* __restrict__ Bt,
                                               TO* __restrict__ C,
                                               int M, int N, int K) {
  __shared__ u16 As[2 * 128 * 32];
  __shared__ u16 Bs[2 * 128 * 32];
  int tid = threadIdx.x, wid = tid >> 6, lane = tid & 63;
  int quad = lane >> 4, l15 = lane & 15;

  // T1 XCD swizzle: contiguous grid chunk per XCD (requires nwg % 8 == 0)
  int nwg = gridDim.x * gridDim.y;
  int bid = blockIdx.y * gridDim.x + blockIdx.x;
  int swz = (bid & 7) * (nwg >> 3) + (bid >> 3);
  int bx = swz % gridDim.x, by = swz / gridDim.x;
  int m0 = by * 128, n0 = bx * 128;
  int wm = (wid >> 1) * 64, wn = (wid & 1) * 64;

  int r0s = wid * 16 + (lane >> 2);
  int r1s = 64 + wid * 16 + (lane >> 2);
  int cblk = lane & 3;
  int cs0 = (cblk ^ ((r0s >> 1) & 3)) * 8;
  int cs1 = (cblk ^ ((r1s >> 1) & 3)) * 8;
  u16* lA0 = As + wid * 512 + lane * 8;
  u16* lA1 = As + (4 + wid) * 512 + lane * 8;
  u16* lB0 = Bs + wid * 512 + lane * 8;
  u16* lB1 = Bs + (4 + wid) * 512 + lane * 8;
  const u16* gA0 = A + (size_t)(m0 + r0s) * K + cs0;
  const u16* gA1 = A + (size_t)(m0 + r1s) * K + cs1;
  const u16* gB0 = Bt + (size_t)(n0 + r0s) * K + cs0;
  const u16* gB1 = Bt + (size_t)(n0 + r1s) * K + cs1;

  f32x4 acc[4][4];
  for (int i = 0; i < 4; i++)
    for (int j = 0; j < 4; j++) acc[i][j] = f32x4{0.f, 0.f, 0.f, 0.f};

  // prologue: stage K-step 0 into buf 0
  gload16(gA0, lA0);
  gload16(gA1, lA1);
  gload16(gB0, lB0);
  gload16(gB1, lB1);
  __builtin_amdgcn_s_waitcnt(0x0F70);  // vmcnt(0)
  __syncthreads();

  int cur = 0;
  for (int k0 = 0; k0 < K; k0 += 32) {
    int nb = cur ^ 1;
    if (k0 + 32 < K) {                 // prefetch next K-step into other buf
      gload16(gA0 + k0 + 32, lA0 + nb * 4096);
      gload16(gA1 + k0 + 32, lA1 + nb * 4096);
      gload16(gB0 + k0 + 32, lB0 + nb * 4096);
      gload16(gB1 + k0 + 32, lB1 + nb * 4096);
    }
    const u16* Ab = As + cur * 4096;
    const u16* Bb = Bs + cur * 4096;
    bf16x8 af[4], bf_[4];
    for (int mi = 0; mi < 4; mi++) {
      int row = wm + mi * 16 + l15;
      af[mi] = *(const bf16x8*)(Ab + row * 32 + ((quad ^ ((row >> 1) & 3)) * 8));
    }
    for (int ni = 0; ni < 4; ni++) {
      int row = wn + ni * 16 + l15;
      bf_[ni] = *(const bf16x8*)(Bb + row * 32 + ((quad ^ ((row >> 1) & 3)) * 8));
    }
    for (int mi = 0; mi < 4; mi++)
      for (int ni = 0; ni < 4; ni++)
        acc[mi][ni] = __builtin_amdgcn_mfma_f32_16x16x32_bf16(af[mi], bf_[ni], acc[mi][ni], 0, 0, 0);
    __builtin_amdgcn_s_waitcnt(0x0F70);  // vmcnt(0): prefetch landed
    __syncthreads();                     // one barrier per K-step
    cur = nb;
  }

  if (ROPE) {
    // rotate (d, d+32) pairs for Q (cols<2048, scale folded) and K (2048..2560)
#pragma unroll
    for (int ni = 0; ni < 2; ni++) {
      int nc = n0 + wn + ni * 16;            // block-uniform
      if (nc < 2560) {
        float scale = (nc < 2048) ? 0.18033688f : 1.0f;  // (1/8)*log2(e) for Q
        float inv = exp2f(-(float)(ni * 16 + l15) * 0.59161152f);  // theta^-(d/32)
#pragma unroll
        for (int mi = 0; mi < 4; mi++)
#pragma unroll
          for (int r = 0; r < 4; r++) {
            int t = (m0 + wm + mi * 16 + quad * 4 + r) & 2047;
            float sn, cs;
            __sincosf((float)t * inv, &sn, &cs);
            float xl = acc[mi][ni][r], xh = acc[mi][ni + 2][r];
            acc[mi][ni][r]     = (xl * cs - xh * sn) * scale;
            acc[mi][ni + 2][r] = (xh * cs + xl * sn) * scale;
          }
      }
    }
  }

  for (int mi = 0; mi < 4; mi++)
    for (int ni = 0; ni < 4; ni++)
      for (int r = 0; r < 4; r++) {
        int row = m0 + wm + mi * 16 + quad * 4 + r;
        int col = n0 + wn + ni * 16 + l15;
        cstore(C, (size_t)row * N + col, acc[mi][ni][r]);
      }
}

// ---------------- Flash attention v7: merged dual-strip passes ----------------
// R8 base (R5 body) ran strips jA=p and jB=15-p as two SEQUENTIAL passes over
// the same key tiles (34 stage+barrier rounds/block). v7 merges them into ONE
// loop over shared K/V tiles (2*(jB+1) rounds, 26% fewer grid-wide):
//  - K-frag and V-frag ds_reads depend only on (dh,hi,l31,sub,kk), NOT the
//    strip -> each LDS read now feeds TWO MFMAs (2x arithmetic intensity);
//  - the two strips' chains are independent -> 2x ILP per latency window at
//    the grid-capped 2 waves/SIMD residency.
// jB>=8>jA: B-strip is never diagonal while A is active (dual path is
// branch-free); after A finishes (kb>q0wA) the loop runs the verbatim
// single-strip body for B. Per-block compute stays uniform (sum of strips).
__global__ __launch_bounds__(256) void attn64(const u16* __restrict__ QKV,
                                              const u16* __restrict__ Vt,
                                              u16* __restrict__ Y) {
  __shared__ u16 Ks[2 * 64 * 64];   // 2 bufs, [key][d], granule-swizzled
  __shared__ u16 Vst[2 * 64 * 64];  // 2 bufs, [d][key], granule-swizzled

  int tid = threadIdx.x, wid = tid >> 6, lane = tid & 63;
  int l31 = lane & 31, hi = lane >> 5;
  int bh = blockIdx.y, b = bh >> 5, h = bh & 31, kvh = h >> 2;
  int p = blockIdx.x;                       // 0..7; p=0 is longest (first)
  int jA = p, jB = 15 - p;

  // K staging (global_load_lds, linear dest + inverse-swizzled src)
  int kr  = wid * 8 + (lane >> 3);
  int kgn = lane & 7;
  const u16* gK0 = QKV + (size_t)(b * 2048 + kr) * 3072 + 2048 + kvh * 64
                 + ((kgn ^ (kr & 7)) * 8);
  u16* lK0 = Ks + wid * 512 + lane * 8;     // +buf*4096; +2048 for rows+32

  // V staging (reg-staged, swizzled ds_write)
  int vr = tid >> 3, vg = tid & 7;
  const u16* gV0 = Vt + (size_t)(kvh * 64 + vr) * 4096 + b * 2048 + vg * 8;
  u16* lV0 = Vst + vr * 64 + ((vg ^ (vr & 7)) * 8);  // +buf*4096; +2048 for d+32

  int q0wA = jA * 128 + wid * 32, qgA = q0wA + l31;
  int q0wB = jB * 128 + wid * 32, qgB = q0wB + l31;

  // Q fragments (RoPE'd + scale-folded by the QKV gemm epilogue)
  bf16x8 qfA[4], qfB[4];
  {
    const u16* qpA = QKV + (size_t)(b * 2048 + qgA) * 3072 + h * 64 + hi * 8;
    const u16* qpB = QKV + (size_t)(b * 2048 + qgB) * 3072 + h * 64 + hi * 8;
#pragma unroll
    for (int dh = 0; dh < 4; dh++) {
      qfA[dh] = *(const bf16x8*)(qpA + dh * 16);
      qfB[dh] = *(const bf16x8*)(qpB + dh * 16);
    }
  }

  f32x16 o0A, o1A, o0B, o1B;
#pragma unroll
  for (int i = 0; i < 16; i++) { o0A[i] = 0.f; o1A[i] = 0.f; o0B[i] = 0.f; o1B[i] = 0.f; }
  float zsumA = 0.f, zsumB = 0.f;

  int nkt = 2 * (jB + 1);                   // covers both strips (jB >= jA)

  // prologue: stage tile 0 into buf 0
  {
    uint4 va = *(const uint4*)(gV0);
    uint4 vb = *(const uint4*)(gV0 + 32 * 4096);
    gload16(gK0, lK0);
    gload16(gK0 + 32 * 3072, lK0 + 2048);
    __builtin_amdgcn_s_waitcnt(0x0F70);     // vmcnt(0)
    *(uint4*)(lV0)        = va;
    *(uint4*)(lV0 + 2048) = vb;
  }
  __syncthreads();

  int cur = 0;
  for (int kt = 0; kt < nkt; kt++) {
    int kbase = kt * 64;
    int nxt = cur ^ 1;
    bool more = (kt + 1 < nkt);
    uint4 va, vb;
    if (more) {                             // issue next tile's loads early
      size_t ko = (size_t)(kbase + 64);
      va = *(const uint4*)(gV0 + ko);
      vb = *(const uint4*)(gV0 + 32 * 4096 + ko);
      gload16(gK0 + ko * 3072, lK0 + nxt * 4096);
      gload16(gK0 + ko * 3072 + 32 * 3072, lK0 + nxt * 4096 + 2048);
    }

    const u16* Kb = Ks + cur * 4096;
    const u16* Vb = Vst + cur * 4096;
#pragma unroll
    for (int sub = 0; sub < 2; sub++) {
      int kb = kbase + sub * 32;
      if (kb > q0wB) break;                 // B is the longer strip
      if (kb <= q0wA) {
        // ---- dual path: shared K/V reads feed both strips ----
        f32x16 sA, sB;
#pragma unroll
        for (int i = 0; i < 16; i++) { sA[i] = 0.f; sB[i] = 0.f; }
#pragma unroll
        for (int dh = 0; dh < 4; dh++) {
          int g = (dh * 2 + hi) ^ (l31 & 7);
          bf16x8 kf = *(const bf16x8*)(Kb + (sub * 32 + l31) * 64 + g * 8);
          sA = __builtin_amdgcn_mfma_f32_32x32x16_bf16(kf, qfA[dh], sA, 0, 0, 0);
          sB = __builtin_amdgcn_mfma_f32_32x32x16_bf16(kf, qfB[dh], sB, 0, 0, 0);
        }
        float pbA[16], pbB[16];
        if (kb < q0wA) {                    // A full subtile
#pragma unroll
          for (int r = 0; r < 16; r++) {
            float pv = exp2f(sA[r]);
            zsumA += pv;
            pbA[r] = pv;
          }
        } else {                            // A diagonal (kb == q0wA)
#pragma unroll
          for (int r = 0; r < 16; r++) {
            int key = kb + (r & 3) + 8 * (r >> 2) + 4 * hi;
            float pv = (key <= qgA) ? exp2f(sA[r]) : 0.f;
            zsumA += pv;
            pbA[r] = pv;
          }
        }
#pragma unroll
        for (int r = 0; r < 16; r++) {      // B always full here (kb < q0wB)
          float pv = exp2f(sB[r]);
          zsumB += pv;
          pbB[r] = pv;
        }
        bf16x8 pfA0 = packP(pbA), pfA1 = packP(pbA + 8);
        bf16x8 pfB0 = packP(pbB), pfB1 = packP(pbB + 8);
#pragma unroll
        for (int kk = 0; kk < 2; kk++) {
          int kgr = sub * 4 + kk * 2 + hi;
          const u16* vp = Vb + l31 * 64 + ((kgr ^ (l31 & 7)) * 8);
          bf16x8 v0 = *(const bf16x8*)(vp);
          bf16x8 v1 = *(const bf16x8*)(vp + 2048);
          bf16x8 pA = kk ? pfA1 : pfA0;
          bf16x8 pB = kk ? pfB1 : pfB0;
          o0A = __builtin_amdgcn_mfma_f32_32x32x16_bf16(pA, v0, o0A, 0, 0, 0);
          o1A = __builtin_amdgcn_mfma_f32_32x32x16_bf16(pA, v1, o1A, 0, 0, 0);
          o0B = __builtin_amdgcn_mfma_f32_32x32x16_bf16(pB, v0, o0B, 0, 0, 0);
          o1B = __builtin_amdgcn_mfma_f32_32x32x16_bf16(pB, v1, o1B, 0, 0, 0);
        }
      } else {
        // ---- B-only path (verbatim single-strip body) ----
        f32x16 s;
#pragma unroll
        for (int i = 0; i < 16; i++) s[i] = 0.f;
#pragma unroll
        for (int dh = 0; dh < 4; dh++) {
          int g = (dh * 2 + hi) ^ (l31 & 7);
          bf16x8 kf = *(const bf16x8*)(Kb + (sub * 32 + l31) * 64 + g * 8);
          s = __builtin_amdgcn_mfma_f32_32x32x16_bf16(kf, qfB[dh], s, 0, 0, 0);
        }
        float pb[16];
        if (kb < q0wB) {
#pragma unroll
          for (int r = 0; r < 16; r++) {
            float pv = exp2f(s[r]);
            zsumB += pv;
            pb[r] = pv;
          }
        } else {                            // B diagonal (kb == q0wB)
#pragma unroll
          for (int r = 0; r < 16; r++) {
            int key = kb + (r & 3) + 8 * (r >> 2) + 4 * hi;
            float pv = (key <= qgB) ? exp2f(s[r]) : 0.f;
            zsumB += pv;
            pb[r] = pv;
          }
        }
        bf16x8 pf0 = packP(pb), pf1 = packP(pb + 8);
#pragma unroll
        for (int kk = 0; kk < 2; kk++) {
          int kgr = sub * 4 + kk * 2 + hi;
          const u16* vp = Vb + l31 * 64 + ((kgr ^ (l31 & 7)) * 8);
          bf16x8 v0 = *(const bf16x8*)(vp);
          bf16x8 v1 = *(const bf16x8*)(vp + 2048);
          bf16x8 pB = kk ? pf1 : pf0;
          o0B = __builtin_amdgcn_mfma_f32_32x32x16_bf16(pB, v0, o0B, 0, 0, 0);
          o1B = __builtin_amdgcn_mfma_f32_32x32x16_bf16(pB, v1, o1B, 0, 0, 0);
        }
      }
    }

    if (more) {
      __builtin_amdgcn_s_waitcnt(0x0F70);   // vmcnt(0): K in LDS, V in regs
      *(uint4*)(lV0 + nxt * 4096)        = va;
      *(uint4*)(lV0 + nxt * 4096 + 2048) = vb;
    }
    __syncthreads();                        // one barrier per shared 64-key tile
    cur = nxt;
  }

  // epilogue, strip A
  {
    float zf = zsumA + __shfl_xor(zsumA, 32);
#pragma unroll
    for (int r = 0; r < 16; r++) {
      int qr = (r & 3) + 8 * (r >> 2) + 4 * hi;
      float zr = __shfl(zf, qr, 64);
      float inv = 1.f / zr;
      size_t row = (size_t)(b * 2048 + q0wA + qr);
      Y[row * 2048 + h * 64 + l31]      = f2bf(o0A[r] * inv);
      Y[row * 2048 + h * 64 + 32 + l31] = f2bf(o1A[r] * inv);
    }
  }
  // epilogue, strip B
  {
    float zf = zsumB + __shfl_xor(zsumB, 32);
#pragma unroll
    for (int r = 0; r < 16; r++) {
      int qr = (r & 3) + 8 * (r >> 2) + 4 * hi;
      float zr = __shfl(zf, qr, 64);
      float inv = 1.f / zr;
      size_t row = (size_t)(b * 2048 + q0wB + qr);
      Y[row * 2048 + h * 64 + l31]      = f2bf(o0B[r] * inv);
      Y[row * 2048 + h * 64 + 32 + l31] = f2bf(o1B[r] * inv);
    }
  }
}

extern "C" void kernel_launch(void* const* d_in, const int* in_sizes, int n_in,
                              void* d_out, int out_size, void* d_ws, size_t ws_size,
                              hipStream_t stream) {
  const float* x  = (const float*)d_in[0];  // [4096][2048] fp32
  const float* Wq = (const float*)d_in[1];  // [2048][2048]
  const float* Wk = (const float*)d_in[2];  // [2048][512]
  const float* Wv = (const float*)d_in[3];  // [2048][512]
  const float* Wo = (const float*)d_in[4];  // [2048][2048]
  float* outp = (float*)d_out;              // fp32 out

  // workspace (u16 units), ~59 MB peak
  u16* xb    = (u16*)d_ws;             // [4096][2048]   8388608
  u16* WqkvT = xb + 8388608;           // [3072][2048]   6291456
  u16* QKV   = WqkvT + 6291456;        // [4096][3072]  12582912
  u16* Vt    = QKV + 12582912;         // [512][4096]    2097152
  u16* Yb    = xb;                     // reuse (xb dead after QKV gemm)
  u16* WoT   = WqkvT;                  // reuse (WqkvT dead after QKV gemm)

  // x -> bf16
  cvt_bf16_f32<<<4096, 256, 0, stream>>>(x, xb, 1048576);

  // weights -> transposed bf16, stacked [Wq^T; Wk^T; Wv^T] (one launch)
  transpose_wqkv<<<dim3(48, 32), 256, 0, stream>>>(Wq, Wk, Wv, WqkvT);

  // fused QKV projection + RoPE(+scale fold) epilogue: [4096,2048]x[2048,3072]
  gemm128<u16, true><<<dim3(24, 32), 256, 0, stream>>>(xb, WqkvT, QKV, 4096, 3072, 2048);

  // V slice -> V^T
  transpose_sl64<<<dim3(8, 64), 256, 0, stream>>>(QKV + 2560, 3072, Vt, 4096, 512);

  // attention v7 (merged dual-strip, KVBLK=64) -> Yb
  attn64<<<dim3(8, 64), 256, 0, stream>>>(QKV, Vt, Yb);

  // Wo -> WoT, output projection -> fp32 d_out
  transpose_cvt64<<<dim3(32, 32), 256, 0, stream>>>(Wo, WoT, 2048, 2048);
  gemm128<float, false><<<dim3(16, 32), 256, 0, stream>>>(Yb, WoT, outp, 4096, 2048, 2048);
}

// Round 10
// 308.253 us; speedup vs baseline: 1.1828x; 1.0034x over previous
//
#include <hip/hip_runtime.h>

using u16 = unsigned short;
using u32 = unsigned int;

typedef __attribute__((ext_vector_type(8))) __bf16 bf16x8;
typedef __attribute__((ext_vector_type(4))) float f32x4;
typedef __attribute__((ext_vector_type(16))) float f32x16;

#define DEVI __device__ __forceinline__

DEVI float bf2f(u16 u) {
  union { u32 i; float f; } v; v.i = ((u32)u) << 16; return v.f;
}
DEVI u16 f2bf(float f) {
  union { float f; u32 u; } v; v.f = f;
  u32 u = v.u;
  u32 r = (u + 0x7fffu + ((u >> 16) & 1u)) >> 16;
  return (u16)r;
}
// pack two f32 -> one u32 of 2x bf16 (compiler emits v_cvt_pk_bf16_f32)
DEVI u32 pkbf(float a, float b) {
  union { __bf16 h[2]; u32 u; } t;
  t.h[0] = (__bf16)a; t.h[1] = (__bf16)b;
  return t.u;
}

// async global->LDS, 16B per lane. LDS dest = wave-uniform base + lane*16.
DEVI void gload16(const u16* g, u16* l) {
  __builtin_amdgcn_global_load_lds(
      (const __attribute__((address_space(1))) void*)g,
      (__attribute__((address_space(3))) void*)l, 16, 0, 0);
}

// P-row (16 f32) -> PV A-fragment via cvt_pk + permlane32_swap (verified R3-R9)
DEVI bf16x8 packP(const float* pp) {
  u32 a01 = pkbf(pp[0], pp[1]);
  u32 a23 = pkbf(pp[2], pp[3]);
  u32 a45 = pkbf(pp[4], pp[5]);
  u32 a67 = pkbf(pp[6], pp[7]);
  asm volatile("v_permlane32_swap_b32 %0, %1" : "+v"(a01), "+v"(a45));
  asm volatile("v_permlane32_swap_b32 %0, %1" : "+v"(a23), "+v"(a67));
  union { u32 w[4]; bf16x8 v; } pf;
  pf.w[0] = a01; pf.w[1] = a23; pf.w[2] = a45; pf.w[3] = a67;
  return pf.v;
}

// tree-sum of 16 floats (depth 4, kills the 32-long serial zsum add chain)
DEVI float sum16(const float* p) {
  float a0 = p[0] + p[1],  a1 = p[2] + p[3];
  float a2 = p[4] + p[5],  a3 = p[6] + p[7];
  float a4 = p[8] + p[9],  a5 = p[10] + p[11];
  float a6 = p[12] + p[13], a7 = p[14] + p[15];
  float b0 = a0 + a1, b1 = a2 + a3, b2 = a4 + a5, b3 = a6 + a7;
  return (b0 + b1) + (b2 + b3);
}

// ------- 64x64 transpose+convert body: in[R][Cc] f32 -> out[Cc][R] bf16 -------
DEVI void tcvt64_body(const float* in, u16* out, int R, int Cc, int c0, int r0, int t,
                      u16 (*tile)[72]) {
  {
    int row = t >> 2, part = t & 3;
    const float* src = in + (size_t)(r0 + row) * Cc + c0 + part * 16;
    float4 f0 = ((const float4*)src)[0];
    float4 f1 = ((const float4*)src)[1];
    float4 f2 = ((const float4*)src)[2];
    float4 f3 = ((const float4*)src)[3];
    u16 v[16] = {f2bf(f0.x), f2bf(f0.y), f2bf(f0.z), f2bf(f0.w),
                 f2bf(f1.x), f2bf(f1.y), f2bf(f1.z), f2bf(f1.w),
                 f2bf(f2.x), f2bf(f2.y), f2bf(f2.z), f2bf(f2.w),
                 f2bf(f3.x), f2bf(f3.y), f2bf(f3.z), f2bf(f3.w)};
    *(uint4*)&tile[row][part * 16]     = ((const uint4*)v)[0];
    *(uint4*)&tile[row][part * 16 + 8] = ((const uint4*)v)[1];
  }
  __syncthreads();
  {
    int c = t & 63, rq = t >> 6;
    u16 v[16];
#pragma unroll
    for (int i = 0; i < 16; i++) v[i] = tile[rq * 16 + i][c];
    u16* dst = out + (size_t)(c0 + c) * R + r0 + rq * 16;
    ((uint4*)dst)[0] = ((const uint4*)v)[0];
    ((uint4*)dst)[1] = ((const uint4*)v)[1];
  }
}

// ---------------- cvt x: fp32 -> bf16, 8 elems/thread ----------------
__global__ __launch_bounds__(256) void cvt_bf16_f32(const float* __restrict__ in,
                                                    u16* __restrict__ out, int n8) {
  int i = blockIdx.x * 256 + threadIdx.x;
  if (i >= n8) return;
  const float4* fin = (const float4*)in;
  float4 a = fin[i * 2], b = fin[i * 2 + 1];
  u16 o[8] = {f2bf(a.x), f2bf(a.y), f2bf(a.z), f2bf(a.w),
              f2bf(b.x), f2bf(b.y), f2bf(b.z), f2bf(b.w)};
  ((uint4*)out)[i] = *(const uint4*)o;
}

__global__ __launch_bounds__(256) void transpose_cvt64(const float* __restrict__ in,
                                                       u16* __restrict__ out,
                                                       int R, int Cc) {
  __shared__ u16 tile[64][72];
  tcvt64_body(in, out, R, Cc, blockIdx.x * 64, blockIdx.y * 64, threadIdx.x, tile);
}

// ---- fused Wq/Wk/Wv transpose (fallback path) ----
__global__ __launch_bounds__(256) void transpose_wqkv(const float* __restrict__ Wq,
                                                      const float* __restrict__ Wk,
                                                      const float* __restrict__ Wv,
                                                      u16* __restrict__ out) {
  __shared__ u16 tile[64][72];
  int bx = blockIdx.x;
  const float* in;
  u16* dst;
  int Cc, c0;
  if (bx < 32)      { in = Wq; dst = out;                        Cc = 2048; c0 = bx * 64; }
  else if (bx < 40) { in = Wk; dst = out + (size_t)2048 * 2048;  Cc = 512;  c0 = (bx - 32) * 64; }
  else              { in = Wv; dst = out + (size_t)2560 * 2048;  Cc = 512;  c0 = (bx - 40) * 64; }
  tcvt64_body(in, dst, 2048, Cc, c0, blockIdx.y * 64, threadIdx.x, tile);
}

// ---- R10: ALL preprocessing in ONE launch (grid-sliced) ----
// blocks [0,4096): cvt x -> bf16; [4096,5632): Wq/Wk/Wv transpose;
// [5632,6656): Wo transpose -> WoT (separate slab, big-ws path only).
__global__ __launch_bounds__(256) void prep_all(const float* __restrict__ x,
                                                const float* __restrict__ Wq,
                                                const float* __restrict__ Wk,
                                                const float* __restrict__ Wv,
                                                const float* __restrict__ Wo,
                                                u16* __restrict__ xb,
                                                u16* __restrict__ WqkvT,
                                                u16* __restrict__ WoT) {
  __shared__ u16 tile[64][72];
  int id = blockIdx.x;
  if (id < 4096) {
    int i = id * 256 + threadIdx.x;
    const float4* fin = (const float4*)x;
    float4 a = fin[i * 2], b = fin[i * 2 + 1];
    u16 o[8] = {f2bf(a.x), f2bf(a.y), f2bf(a.z), f2bf(a.w),
                f2bf(b.x), f2bf(b.y), f2bf(b.z), f2bf(b.w)};
    ((uint4*)xb)[i] = *(const uint4*)o;
    return;
  }
  id -= 4096;
  if (id < 1536) {
    int bx = id % 48, by = id / 48;
    const float* in;
    u16* dst;
    int Cc, c0;
    if (bx < 32)      { in = Wq; dst = WqkvT;                        Cc = 2048; c0 = bx * 64; }
    else if (bx < 40) { in = Wk; dst = WqkvT + (size_t)2048 * 2048;  Cc = 512;  c0 = (bx - 32) * 64; }
    else              { in = Wv; dst = WqkvT + (size_t)2560 * 2048;  Cc = 512;  c0 = (bx - 40) * 64; }
    tcvt64_body(in, dst, 2048, Cc, c0, by * 64, threadIdx.x, tile);
    return;
  }
  id -= 1536;
  int bx = id & 31, by = id >> 5;
  tcvt64_body(Wo, WoT, 2048, 2048, bx * 64, by * 64, threadIdx.x, tile);
}

// ---- 64x64 vectorized bf16 transpose with input row-stride (V slice) ----
__global__ __launch_bounds__(256) void transpose_sl64(const u16* __restrict__ in, int ldin,
                                                      u16* __restrict__ out,
                                                      int R, int Cc) {
  __shared__ u16 tile[64][72];
  int c0 = blockIdx.x * 64, r0 = blockIdx.y * 64;
  int t = threadIdx.x;
  {
    int row = t >> 2, part = t & 3;
    const u16* src = in + (size_t)(r0 + row) * ldin + c0 + part * 16;
    uint4 a = ((const uint4*)src)[0];
    uint4 b = ((const uint4*)src)[1];
    *(uint4*)&tile[row][part * 16]     = a;
    *(uint4*)&tile[row][part * 16 + 8] = b;
  }
  __syncthreads();
  {
    int c = t & 63, rq = t >> 6;
    u16 v[16];
#pragma unroll
    for (int i = 0; i < 16; i++) v[i] = tile[rq * 16 + i][c];
    u16* dst = out + (size_t)(c0 + c) * R + r0 + rq * 16;
    ((uint4*)dst)[0] = ((const uint4*)v)[0];
    ((uint4*)dst)[1] = ((const uint4*)v)[1];
  }
}

// ---- GEMM: C[M,N] = A[M,K] * Bt[N,K]^T, 128x128 tile, BK=32, 2-phase dbuf ----
// R8-verified: T1 XCD swizzle (bijective) + ROPE epilogue on the QKV call.
// Frozen (8-phase 256^2 rejected: 192/128 blocks under-subscribe 256 CUs).
DEVI void cstore(u16* C, size_t idx, float v)   { C[idx] = f2bf(v); }
DEVI void cstore(float* C, size_t idx, float v) { C[idx] = v; }

template <typename TO, bool ROPE>
__global__ __launch_bounds__(256) void gemm128(const u16* __restrict__ A,
                                               const u16* __restrict__ Bt,
                                               TO* __restrict__ C,
                                               int M, int N, int K) {
  __shared__ u16 As[2 * 128 * 32];
  __shared__ u16 Bs[2 * 128 * 32];
  int tid = threadIdx.x, wid = tid >> 6, lane = tid & 63;
  int quad = lane >> 4, l15 = lane & 15;

  // T1 XCD swizzle: contiguous grid chunk per XCD (requires nwg % 8 == 0)
  int nwg = gridDim.x * gridDim.y;
  int bid = blockIdx.y * gridDim.x + blockIdx.x;
  int swz = (bid & 7) * (nwg >> 3) + (bid >> 3);
  int bx = swz % gridDim.x, by = swz / gridDim.x;
  int m0 = by * 128, n0 = bx * 128;
  int wm = (wid >> 1) * 64, wn = (wid & 1) * 64;

  int r0s = wid * 16 + (lane >> 2);
  int r1s = 64 + wid * 16 + (lane >> 2);
  int cblk = lane & 3;
  int cs0 = (cblk ^ ((r0s >> 1) & 3)) * 8;
  int cs1 = (cblk ^ ((r1s >> 1) & 3)) * 8;
  u16* lA0 = As + wid * 512 + lane * 8;
  u16* lA1 = As + (4 + wid) * 512 + lane * 8;
  u16* lB0 = Bs + wid * 512 + lane * 8;
  u16* lB1 = Bs + (4 + wid) * 512 + lane * 8;
  const u16* gA0 = A + (size_t)(m0 + r0s) * K + cs0;
  const u16* gA1 = A + (size_t)(m0 + r1s) * K + cs1;
  const u16* gB0 = Bt + (size_t)(n0 + r0s) * K + cs0;
  const u16* gB1 = Bt + (size_t)(n0 + r1s) * K + cs1;

  f32x4 acc[4][4];
  for (int i = 0; i < 4; i++)
    for (int j = 0; j < 4; j++) acc[i][j] = f32x4{0.f, 0.f, 0.f, 0.f};

  // prologue: stage K-step 0 into buf 0
  gload16(gA0, lA0);
  gload16(gA1, lA1);
  gload16(gB0, lB0);
  gload16(gB1, lB1);
  __builtin_amdgcn_s_waitcnt(0x0F70);  // vmcnt(0)
  __syncthreads();

  int cur = 0;
  for (int k0 = 0; k0 < K; k0 += 32) {
    int nb = cur ^ 1;
    if (k0 + 32 < K) {                 // prefetch next K-step into other buf
      gload16(gA0 + k0 + 32, lA0 + nb * 4096);
      gload16(gA1 + k0 + 32, lA1 + nb * 4096);
      gload16(gB0 + k0 + 32, lB0 + nb * 4096);
      gload16(gB1 + k0 + 32, lB1 + nb * 4096);
    }
    const u16* Ab = As + cur * 4096;
    const u16* Bb = Bs + cur * 4096;
    bf16x8 af[4], bf_[4];
    for (int mi = 0; mi < 4; mi++) {
      int row = wm + mi * 16 + l15;
      af[mi] = *(const bf16x8*)(Ab + row * 32 + ((quad ^ ((row >> 1) & 3)) * 8));
    }
    for (int ni = 0; ni < 4; ni++) {
      int row = wn + ni * 16 + l15;
      bf_[ni] = *(const bf16x8*)(Bb + row * 32 + ((quad ^ ((row >> 1) & 3)) * 8));
    }
    for (int mi = 0; mi < 4; mi++)
      for (int ni = 0; ni < 4; ni++)
        acc[mi][ni] = __builtin_amdgcn_mfma_f32_16x16x32_bf16(af[mi], bf_[ni], acc[mi][ni], 0, 0, 0);
    __builtin_amdgcn_s_waitcnt(0x0F70);  // vmcnt(0): prefetch landed
    __syncthreads();                     // one barrier per K-step
    cur = nb;
  }

  if (ROPE) {
    // rotate (d, d+32) pairs for Q (cols<2048, scale folded) and K (2048..2560)
#pragma unroll
    for (int ni = 0; ni < 2; ni++) {
      int nc = n0 + wn + ni * 16;            // block-uniform
      if (nc < 2560) {
        float scale = (nc < 2048) ? 0.18033688f : 1.0f;  // (1/8)*log2(e) for Q
        float inv = exp2f(-(float)(ni * 16 + l15) * 0.59161152f);  // theta^-(d/32)
#pragma unroll
        for (int mi = 0; mi < 4; mi++)
#pragma unroll
          for (int r = 0; r < 4; r++) {
            int t = (m0 + wm + mi * 16 + quad * 4 + r) & 2047;
            float sn, cs;
            __sincosf((float)t * inv, &sn, &cs);
            float xl = acc[mi][ni][r], xh = acc[mi][ni + 2][r];
            acc[mi][ni][r]     = (xl * cs - xh * sn) * scale;
            acc[mi][ni + 2][r] = (xh * cs + xl * sn) * scale;
          }
      }
    }
  }

  for (int mi = 0; mi < 4; mi++)
    for (int ni = 0; ni < 4; ni++)
      for (int r = 0; r < 4; r++) {
        int row = m0 + wm + mi * 16 + quad * 4 + r;
        int col = n0 + wn + ni * 16 + l15;
        cstore(C, (size_t)row * N + col, acc[mi][ni][r]);
      }
}

// ---------------- Flash attention v8: dual-strip + tree-zsum + setprio ----------------
// R9-verified merged dual-strip body. R10 deltas (mechanisms from counters):
//  - zsum serial chain (32 dependent v_add ~ 128 cyc/subtile) -> depth-4 tree sum;
//  - T5 s_setprio(1) around MFMA clusters (waves drift within a tile -> role
//    diversity; m191-style attn case, unlike the lockstep GEMM null).
__global__ __launch_bounds__(256) void attn64(const u16* __restrict__ QKV,
                                              const u16* __restrict__ Vt,
                                              u16* __restrict__ Y) {
  __shared__ u16 Ks[2 * 64 * 64];   // 2 bufs, [key][d], granule-swizzled
  __shared__ u16 Vst[2 * 64 * 64];  // 2 bufs, [d][key], granule-swizzled

  int tid = threadIdx.x, wid = tid >> 6, lane = tid & 63;
  int l31 = lane & 31, hi = lane >> 5;
  int bh = blockIdx.y, b = bh >> 5, h = bh & 31, kvh = h >> 2;
  int p = blockIdx.x;                       // 0..7
  int jA = p, jB = 15 - p;

  // K staging (global_load_lds, linear dest + inverse-swizzled src)
  int kr  = wid * 8 + (lane >> 3);
  int kgn = lane & 7;
  const u16* gK0 = QKV + (size_t)(b * 2048 + kr) * 3072 + 2048 + kvh * 64
                 + ((kgn ^ (kr & 7)) * 8);
  u16* lK0 = Ks + wid * 512 + lane * 8;     // +buf*4096; +2048 for rows+32

  // V staging (reg-staged, swizzled ds_write)
  int vr = tid >> 3, vg = tid & 7;
  const u16* gV0 = Vt + (size_t)(kvh * 64 + vr) * 4096 + b * 2048 + vg * 8;
  u16* lV0 = Vst + vr * 64 + ((vg ^ (vr & 7)) * 8);  // +buf*4096; +2048 for d+32

  int q0wA = jA * 128 + wid * 32, qgA = q0wA + l31;
  int q0wB = jB * 128 + wid * 32, qgB = q0wB + l31;

  // Q fragments (RoPE'd + scale-folded by the QKV gemm epilogue)
  bf16x8 qfA[4], qfB[4];
  {
    const u16* qpA = QKV + (size_t)(b * 2048 + qgA) * 3072 + h * 64 + hi * 8;
    const u16* qpB = QKV + (size_t)(b * 2048 + qgB) * 3072 + h * 64 + hi * 8;
#pragma unroll
    for (int dh = 0; dh < 4; dh++) {
      qfA[dh] = *(const bf16x8*)(qpA + dh * 16);
      qfB[dh] = *(const bf16x8*)(qpB + dh * 16);
    }
  }

  f32x16 o0A, o1A, o0B, o1B;
#pragma unroll
  for (int i = 0; i < 16; i++) { o0A[i] = 0.f; o1A[i] = 0.f; o0B[i] = 0.f; o1B[i] = 0.f; }
  float zsumA = 0.f, zsumB = 0.f;

  int nkt = 2 * (jB + 1);                   // covers both strips (jB >= jA)

  // prologue: stage tile 0 into buf 0
  {
    uint4 va = *(const uint4*)(gV0);
    uint4 vb = *(const uint4*)(gV0 + 32 * 4096);
    gload16(gK0, lK0);
    gload16(gK0 + 32 * 3072, lK0 + 2048);
    __builtin_amdgcn_s_waitcnt(0x0F70);     // vmcnt(0)
    *(uint4*)(lV0)        = va;
    *(uint4*)(lV0 + 2048) = vb;
  }
  __syncthreads();

  int cur = 0;
  for (int kt = 0; kt < nkt; kt++) {
    int kbase = kt * 64;
    int nxt = cur ^ 1;
    bool more = (kt + 1 < nkt);
    uint4 va, vb;
    if (more) {                             // issue next tile's loads early
      size_t ko = (size_t)(kbase + 64);
      va = *(const uint4*)(gV0 + ko);
      vb = *(const uint4*)(gV0 + 32 * 4096 + ko);
      gload16(gK0 + ko * 3072, lK0 + nxt * 4096);
      gload16(gK0 + ko * 3072 + 32 * 3072, lK0 + nxt * 4096 + 2048);
    }

    const u16* Kb = Ks + cur * 4096;
    const u16* Vb = Vst + cur * 4096;
#pragma unroll
    for (int sub = 0; sub < 2; sub++) {
      int kb = kbase + sub * 32;
      if (kb > q0wB) break;                 // B is the longer strip
      if (kb <= q0wA) {
        // ---- dual path: shared K/V reads feed both strips ----
        f32x16 sA, sB;
#pragma unroll
        for (int i = 0; i < 16; i++) { sA[i] = 0.f; sB[i] = 0.f; }
        __builtin_amdgcn_s_setprio(1);
#pragma unroll
        for (int dh = 0; dh < 4; dh++) {
          int g = (dh * 2 + hi) ^ (l31 & 7);
          bf16x8 kf = *(const bf16x8*)(Kb + (sub * 32 + l31) * 64 + g * 8);
          sA = __builtin_amdgcn_mfma_f32_32x32x16_bf16(kf, qfA[dh], sA, 0, 0, 0);
          sB = __builtin_amdgcn_mfma_f32_32x32x16_bf16(kf, qfB[dh], sB, 0, 0, 0);
        }
        __builtin_amdgcn_s_setprio(0);
        float pbA[16], pbB[16];
        if (kb < q0wA) {                    // A full subtile
#pragma unroll
          for (int r = 0; r < 16; r++) pbA[r] = exp2f(sA[r]);
        } else {                            // A diagonal (kb == q0wA)
#pragma unroll
          for (int r = 0; r < 16; r++) {
            int key = kb + (r & 3) + 8 * (r >> 2) + 4 * hi;
            pbA[r] = (key <= qgA) ? exp2f(sA[r]) : 0.f;
          }
        }
#pragma unroll
        for (int r = 0; r < 16; r++) pbB[r] = exp2f(sB[r]);
        zsumA += sum16(pbA);
        zsumB += sum16(pbB);
        bf16x8 pfA0 = packP(pbA), pfA1 = packP(pbA + 8);
        bf16x8 pfB0 = packP(pbB), pfB1 = packP(pbB + 8);
        __builtin_amdgcn_s_setprio(1);
#pragma unroll
        for (int kk = 0; kk < 2; kk++) {
          int kgr = sub * 4 + kk * 2 + hi;
          const u16* vp = Vb + l31 * 64 + ((kgr ^ (l31 & 7)) * 8);
          bf16x8 v0 = *(const bf16x8*)(vp);
          bf16x8 v1 = *(const bf16x8*)(vp + 2048);
          bf16x8 pA = kk ? pfA1 : pfA0;
          bf16x8 pB = kk ? pfB1 : pfB0;
          o0A = __builtin_amdgcn_mfma_f32_32x32x16_bf16(pA, v0, o0A, 0, 0, 0);
          o1A = __builtin_amdgcn_mfma_f32_32x32x16_bf16(pA, v1, o1A, 0, 0, 0);
          o0B = __builtin_amdgcn_mfma_f32_32x32x16_bf16(pB, v0, o0B, 0, 0, 0);
          o1B = __builtin_amdgcn_mfma_f32_32x32x16_bf16(pB, v1, o1B, 0, 0, 0);
        }
        __builtin_amdgcn_s_setprio(0);
      } else {
        // ---- B-only path ----
        f32x16 s;
#pragma unroll
        for (int i = 0; i < 16; i++) s[i] = 0.f;
        __builtin_amdgcn_s_setprio(1);
#pragma unroll
        for (int dh = 0; dh < 4; dh++) {
          int g = (dh * 2 + hi) ^ (l31 & 7);
          bf16x8 kf = *(const bf16x8*)(Kb + (sub * 32 + l31) * 64 + g * 8);
          s = __builtin_amdgcn_mfma_f32_32x32x16_bf16(kf, qfB[dh], s, 0, 0, 0);
        }
        __builtin_amdgcn_s_setprio(0);
        float pb[16];
        if (kb < q0wB) {
#pragma unroll
          for (int r = 0; r < 16; r++) pb[r] = exp2f(s[r]);
        } else {                            // B diagonal (kb == q0wB)
#pragma unroll
          for (int r = 0; r < 16; r++) {
            int key = kb + (r & 3) + 8 * (r >> 2) + 4 * hi;
            pb[r] = (key <= qgB) ? exp2f(s[r]) : 0.f;
          }
        }
        zsumB += sum16(pb);
        bf16x8 pf0 = packP(pb), pf1 = packP(pb + 8);
        __builtin_amdgcn_s_setprio(1);
#pragma unroll
        for (int kk = 0; kk < 2; kk++) {
          int kgr = sub * 4 + kk * 2 + hi;
          const u16* vp = Vb + l31 * 64 + ((kgr ^ (l31 & 7)) * 8);
          bf16x8 v0 = *(const bf16x8*)(vp);
          bf16x8 v1 = *(const bf16x8*)(vp + 2048);
          bf16x8 pB = kk ? pf1 : pf0;
          o0B = __builtin_amdgcn_mfma_f32_32x32x16_bf16(pB, v0, o0B, 0, 0, 0);
          o1B = __builtin_amdgcn_mfma_f32_32x32x16_bf16(pB, v1, o1B, 0, 0, 0);
        }
        __builtin_amdgcn_s_setprio(0);
      }
    }

    if (more) {
      __builtin_amdgcn_s_waitcnt(0x0F70);   // vmcnt(0): K in LDS, V in regs
      *(uint4*)(lV0 + nxt * 4096)        = va;
      *(uint4*)(lV0 + nxt * 4096 + 2048) = vb;
    }
    __syncthreads();                        // one barrier per shared 64-key tile
    cur = nxt;
  }

  // epilogue, strip A
  {
    float zf = zsumA + __shfl_xor(zsumA, 32);
#pragma unroll
    for (int r = 0; r < 16; r++) {
      int qr = (r & 3) + 8 * (r >> 2) + 4 * hi;
      float zr = __shfl(zf, qr, 64);
      float inv = 1.f / zr;
      size_t row = (size_t)(b * 2048 + q0wA + qr);
      Y[row * 2048 + h * 64 + l31]      = f2bf(o0A[r] * inv);
      Y[row * 2048 + h * 64 + 32 + l31] = f2bf(o1A[r] * inv);
    }
  }
  // epilogue, strip B
  {
    float zf = zsumB + __shfl_xor(zsumB, 32);
#pragma unroll
    for (int r = 0; r < 16; r++) {
      int qr = (r & 3) + 8 * (r >> 2) + 4 * hi;
      float zr = __shfl(zf, qr, 64);
      float inv = 1.f / zr;
      size_t row = (size_t)(b * 2048 + q0wB + qr);
      Y[row * 2048 + h * 64 + l31]      = f2bf(o0B[r] * inv);
      Y[row * 2048 + h * 64 + 32 + l31] = f2bf(o1B[r] * inv);
    }
  }
}

extern "C" void kernel_launch(void* const* d_in, const int* in_sizes, int n_in,
                              void* d_out, int out_size, void* d_ws, size_t ws_size,
                              hipStream_t stream) {
  const float* x  = (const float*)d_in[0];  // [4096][2048] fp32
  const float* Wq = (const float*)d_in[1];  // [2048][2048]
  const float* Wk = (const float*)d_in[2];  // [2048][512]
  const float* Wv = (const float*)d_in[3];  // [2048][512]
  const float* Wo = (const float*)d_in[4];  // [2048][2048]
  float* outp = (float*)d_out;              // fp32 out

  // workspace (u16 units)
  u16* xb    = (u16*)d_ws;             // [4096][2048]   8388608
  u16* WqkvT = xb + 8388608;           // [3072][2048]   6291456
  u16* QKV   = WqkvT + 6291456;        // [4096][3072]  12582912
  u16* Vt    = QKV + 12582912;         // [512][4096]    2097152
  u16* Yb    = xb;                     // reuse (xb dead after QKV gemm)

  // big-ws path: WoT gets its own slab -> all preprocessing in one launch
  bool bigws = ws_size >= (size_t)(33554432) * 2;  // 64 MB
  u16* WoT = bigws ? (Vt + 2097152) : WqkvT;       // fallback: alias WqkvT

  if (bigws) {
    // ALL preprocessing (cvt x, Wqkv^T, Wo^T) in one launch
    prep_all<<<6656, 256, 0, stream>>>(x, Wq, Wk, Wv, Wo, xb, WqkvT, WoT);
  } else {
    cvt_bf16_f32<<<4096, 256, 0, stream>>>(x, xb, 1048576);
    transpose_wqkv<<<dim3(48, 32), 256, 0, stream>>>(Wq, Wk, Wv, WqkvT);
  }

  // fused QKV projection + RoPE(+scale fold) epilogue: [4096,2048]x[2048,3072]
  gemm128<u16, true><<<dim3(24, 32), 256, 0, stream>>>(xb, WqkvT, QKV, 4096, 3072, 2048);

  // V slice -> V^T
  transpose_sl64<<<dim3(8, 64), 256, 0, stream>>>(QKV + 2560, 3072, Vt, 4096, 512);

  // attention v8 (dual-strip + tree-zsum + setprio) -> Yb
  attn64<<<dim3(8, 64), 256, 0, stream>>>(QKV, Vt, Yb);

  if (!bigws) {
    // fallback: Wo transpose after QKV gemm freed WqkvT
    transpose_cvt64<<<dim3(32, 32), 256, 0, stream>>>(Wo, WoT, 2048, 2048);
  }
  // output projection -> fp32 d_out
  gemm128<float, false><<<dim3(16, 32), 256, 0, stream>>>(Yb, WoT, outp, 4096, 2048, 2048);
}